// Round 5
// baseline (957.236 us; speedup 1.0000x reference)
//
#include <hip/hip_runtime.h>
#include <hip/hip_bf16.h>

#define B_ 16
#define S_ 4096
#define DM_ 1280
#define DC_ 768
#define NC_ 384
#define SCALE_ 0.07905694150420949f

typedef __attribute__((ext_vector_type(8))) short bf16x8;
typedef __attribute__((ext_vector_type(4))) float f32x4;
typedef __attribute__((ext_vector_type(4))) unsigned short u16x4;

__device__ __forceinline__ unsigned short f2bf(float f) {
    unsigned int u = __builtin_bit_cast(unsigned int, f);
    u = (u + 0x7FFFu + ((u >> 16) & 1u)) >> 16;
    return (unsigned short)u;
}

__device__ __forceinline__ bf16x8 pack8(float4 x0, float4 x1) {
    bf16x8 a;
    a[0] = (short)f2bf(x0.x); a[1] = (short)f2bf(x0.y);
    a[2] = (short)f2bf(x0.z); a[3] = (short)f2bf(x0.w);
    a[4] = (short)f2bf(x1.x); a[5] = (short)f2bf(x1.y);
    a[6] = (short)f2bf(x1.z); a[7] = (short)f2bf(x1.w);
    return a;
}

// ---------- merged prep: wq cvt + 5 transpose/cvt ----------
__device__ __forceinline__ void tcvt_body(const float* __restrict__ in,
                                          unsigned short* __restrict__ out,
                                          int R, int C, int bx, int by, int tid) {
    __shared__ float tile[32][33];
    int c0 = bx * 32, r0 = by * 32;
    int tx = tid & 31, ty = tid >> 5;
    for (int i = ty; i < 32; i += 8)
        tile[i][tx] = in[(size_t)(r0 + i) * C + c0 + tx];
    __syncthreads();
    for (int i = ty; i < 32; i += 8)
        out[(size_t)(c0 + i) * R + r0 + tx] = f2bf(tile[tx][i]);
}

__global__ __launch_bounds__(256)
void k_prep(const float* __restrict__ wq, const float* __restrict__ wk,
            const float* __restrict__ wv, const float* __restrict__ wkd,
            const float* __restrict__ wvd, const float* __restrict__ wout,
            unsigned short* __restrict__ wq_bf, unsigned short* __restrict__ wTk,
            unsigned short* __restrict__ wTv, unsigned short* __restrict__ wTkd,
            unsigned short* __restrict__ wTvd, unsigned short* __restrict__ woutT) {
    int bid = blockIdx.x, tid = threadIdx.x;
    if (bid < 1600) {                       // wq f32 -> bf16
        int i = bid * 256 + tid;
        float4 v = ((const float4*)wq)[i];
        u16x4 o = { f2bf(v.x), f2bf(v.y), f2bf(v.z), f2bf(v.w) };
        ((u16x4*)wq_bf)[i] = o;
    } else if (bid < 2560) {
        int r = bid - 1600; tcvt_body(wk,  wTk,  DC_, DM_, r % 40, r / 40, tid);
    } else if (bid < 3520) {
        int r = bid - 2560; tcvt_body(wv,  wTv,  DC_, DM_, r % 40, r / 40, tid);
    } else if (bid < 4480) {
        int r = bid - 3520; tcvt_body(wkd, wTkd, DC_, DM_, r % 40, r / 40, tid);
    } else if (bid < 5440) {
        int r = bid - 4480; tcvt_body(wvd, wTvd, DC_, DM_, r % 40, r / 40, tid);
    } else {
        int r = bid - 5440; tcvt_body(wout, woutT, DM_, DM_, r % 40, r / 40, tid);
    }
}

// ---------- K/V projections via MFMA ----------
__global__ __launch_bounds__(256)
void k_projM(const float* __restrict__ enc,
             const unsigned short* __restrict__ wTk, const unsigned short* __restrict__ wTv,
             const unsigned short* __restrict__ wTkd, const unsigned short* __restrict__ wTvd,
             unsigned short* __restrict__ KV) {
    int bid = blockIdx.x;
    int j = bid / 80, rem = bid % 80, b = rem / 5, nt = rem % 5;
    int tid = threadIdx.x, w = tid >> 6, l = tid & 63, l15 = l & 15, l4 = l >> 4;
    int tok0 = (j < 2) ? 16 : ((j < 4) ? 0 : 32);
    const unsigned short* wT = (j == 0) ? wTk : (j == 1) ? wTv : (j == 2 || j == 4) ? wTkd : wTvd;
    const float* ap = enc + ((size_t)(b * 48 + tok0 + l15)) * DC_;
    f32x4 zero = {0.f, 0.f, 0.f, 0.f};
    f32x4 acc[4];
    #pragma unroll
    for (int t = 0; t < 4; t++) acc[t] = zero;
    for (int kk = 0; kk < 24; kk++) {
        const float4* hp = (const float4*)(ap + kk * 32 + l4 * 8);
        bf16x8 af = pack8(hp[0], hp[1]);
        #pragma unroll
        for (int t = 0; t < 4; t++) {
            int n0 = nt * 256 + w * 64 + t * 16;
            bf16x8 bf = *(const bf16x8*)(wT + (size_t)(n0 + l15) * DC_ + kk * 32 + l4 * 8);
            acc[t] = __builtin_amdgcn_mfma_f32_16x16x32_bf16(af, bf, acc[t], 0, 0, 0);
        }
    }
    #pragma unroll
    for (int t = 0; t < 4; t++) {
        int e = nt * 256 + w * 64 + t * 16 + l15;
        #pragma unroll
        for (int r = 0; r < 4; r++)
            KV[((size_t)(j * 16 + b) * 16 + l4 * 4 + r) * DM_ + e] = f2bf(acc[t][r]);
    }
}

// ---------- merged A/U build via MFMA ----------
__global__ __launch_bounds__(256)
void k_au(const unsigned short* __restrict__ KV, const unsigned short* __restrict__ wqbf,
          const unsigned short* __restrict__ woutT,
          unsigned short* __restrict__ At, unsigned short* __restrict__ Ut) {
    int bid0 = blockIdx.x;
    bool isA = bid0 < 384;
    int bid = isA ? bid0 : bid0 - 384;
    int b = bid & 15, r_ = bid >> 4, x = r_ >> 3, h = r_ & 7;
    int tid = threadIdx.x, w = tid >> 6, l = tid & 63, l15 = l & 15, l4 = l >> 4;
    int jrow = isA ? (2 * x) : (2 * x + 1);
    const unsigned short* wmat = isA ? wqbf : woutT;
    float postscale = isA ? SCALE_ : ((x == 2) ? 1.0f : 0.5f);
    bf16x8 bfr[5];
    #pragma unroll
    for (int kk = 0; kk < 5; kk++)
        bfr[kk] = *(const bf16x8*)(KV + ((size_t)(jrow * 16 + b) * 16 + l15) * DM_ + h * 160 + kk * 32 + l4 * 8);
    f32x4 zero = {0.f, 0.f, 0.f, 0.f};
    for (int tt = 0; tt < 20; tt++) {
        int d0 = w * 320 + tt * 16;
        f32x4 acc = zero;
        #pragma unroll
        for (int kk = 0; kk < 5; kk++) {
            bf16x8 af = *(const bf16x8*)(wmat + (size_t)(d0 + l15) * DM_ + h * 160 + kk * 32 + l4 * 8);
            acc = __builtin_amdgcn_mfma_f32_16x16x32_bf16(af, bfr[kk], acc, 0, 0, 0);
        }
        if (isA) {
            u16x4 pk;
            #pragma unroll
            for (int r = 0; r < 4; r++) pk[r] = f2bf(acc[r] * postscale);
            *(u16x4*)(At + ((size_t)b * NC_ + (x * 8 + h) * 16 + l15) * DM_ + d0 + l4 * 4) = pk;
        } else {
            int c = (x * 8 + h) * 16 + l15;
            #pragma unroll
            for (int r = 0; r < 4; r++)
                Ut[((size_t)b * DM_ + d0 + l4 * 4 + r) * NC_ + c] = f2bf(acc[r] * postscale);
        }
    }
}

// ---------- scores: register-only, no LDS, no barriers ----------
__global__ __launch_bounds__(256, 2)
void k_scores2(const float* __restrict__ hid, const unsigned short* __restrict__ At,
               unsigned short* __restrict__ P) {
    int bid = blockIdx.x;
    int b = bid & 15, t = bid >> 4;
    int s0 = t * 64;
    int tid = threadIdx.x;
    int w = tid >> 6, l = tid & 63;
    int l15 = l & 15, l4 = l >> 4;
    f32x4 zero = {0.f, 0.f, 0.f, 0.f};
    f32x4 acc[24];
    #pragma unroll
    for (int g = 0; g < 24; g++) acc[g] = zero;
    const unsigned short* Ab = At + (size_t)b * NC_ * DM_ + (size_t)l15 * DM_ + l4 * 8;
    const float* hrow = hid + ((size_t)b * S_ + s0 + w * 16 + l15) * DM_;

    for (int kk = 0; kk < 40; kk++) {
        const float4* hp = (const float4*)(hrow + kk * 32 + l4 * 8);
        float4 x0 = hp[0], x1 = hp[1];
        bf16x8 af = pack8(x0, x1);
        #pragma unroll
        for (int g = 0; g < 24; g++) {
            bf16x8 bf = *(const bf16x8*)(Ab + (size_t)g * 16 * DM_ + kk * 32);
            acc[g] = __builtin_amdgcn_mfma_f32_16x16x32_bf16(bf, af, acc[g], 0, 0, 0);
        }
    }

    // acc[g][r]: c = g*16 + l4*4 + r, s = s0 + w*16 + l15 -> softmax over each 16-c group
    unsigned short* Pb = P + ((size_t)b * S_ + s0 + w * 16 + l15) * NC_;
    #pragma unroll
    for (int g = 0; g < 24; g++) {
        float v0 = acc[g][0], v1 = acc[g][1], v2 = acc[g][2], v3 = acc[g][3];
        float mx = fmaxf(fmaxf(v0, v1), fmaxf(v2, v3));
        mx = fmaxf(mx, __shfl_xor(mx, 16));
        mx = fmaxf(mx, __shfl_xor(mx, 32));
        float e0 = __expf(v0 - mx), e1 = __expf(v1 - mx), e2 = __expf(v2 - mx), e3 = __expf(v3 - mx);
        float sm = e0 + e1 + e2 + e3;
        sm += __shfl_xor(sm, 16);
        sm += __shfl_xor(sm, 32);
        float rs = 1.0f / sm;
        u16x4 pk = { f2bf(e0 * rs), f2bf(e1 * rs), f2bf(e2 * rs), f2bf(e3 * rs) };
        *(u16x4*)(Pb + g * 16 + l4 * 4) = pk;
    }
}

// ---------- PV: U register-persistent, no LDS, no barriers ----------
__global__ __launch_bounds__(256, 2)
void k_pv(const unsigned short* __restrict__ P, const unsigned short* __restrict__ Ut,
          const float* __restrict__ hid, const float* __restrict__ bo,
          float* __restrict__ out) {
    int bid = blockIdx.x;                 // bid = ((b*8 + st)*10 + ec)
    int ec = bid % 10;
    int rest = bid / 10;
    int st = rest & 7, b = rest >> 3;
    int tid = threadIdx.x;
    int w = tid >> 6, l = tid & 63;
    int l15 = l & 15, l4 = l >> 4;
    f32x4 zero = {0.f, 0.f, 0.f, 0.f};

    int ebase = ec * 128 + w * 32;
    const unsigned short* Ub = Ut + (size_t)b * DM_ * NC_;

    // U fragments: wave covers e in [ebase, ebase+32), all 384 c. 24 x bf16x8 = 96 VGPR.
    bf16x8 uf[2][12];
    #pragma unroll
    for (int mt = 0; mt < 2; mt++)
        #pragma unroll
        for (int kk = 0; kk < 12; kk++)
            uf[mt][kk] = *(const bf16x8*)(Ub + (size_t)(ebase + mt * 16 + l15) * NC_ + kk * 32 + l4 * 8);

    float4 bias[2];
    #pragma unroll
    for (int mt = 0; mt < 2; mt++)
        bias[mt] = *(const float4*)(bo + ebase + mt * 16 + l4 * 4);

    for (int sti = 0; sti < 8; sti++) {
        int s0 = (st * 8 + sti) * 64;
        const unsigned short* Pb = P + ((size_t)b * S_ + s0 + l15) * NC_ + l4 * 8;
        f32x4 acc[4][2];
        #pragma unroll
        for (int sg = 0; sg < 4; sg++) {
            acc[sg][0] = zero; acc[sg][1] = zero;
        }
        #pragma unroll
        for (int kk = 0; kk < 12; kk++) {
            bf16x8 pv0 = *(const bf16x8*)(Pb + (size_t)(0 * 16) * NC_ + kk * 32);
            bf16x8 pv1 = *(const bf16x8*)(Pb + (size_t)(1 * 16) * NC_ + kk * 32);
            bf16x8 pv2 = *(const bf16x8*)(Pb + (size_t)(2 * 16) * NC_ + kk * 32);
            bf16x8 pv3 = *(const bf16x8*)(Pb + (size_t)(3 * 16) * NC_ + kk * 32);
            #pragma unroll
            for (int mt = 0; mt < 2; mt++) {
                acc[0][mt] = __builtin_amdgcn_mfma_f32_16x16x32_bf16(uf[mt][kk], pv0, acc[0][mt], 0, 0, 0);
                acc[1][mt] = __builtin_amdgcn_mfma_f32_16x16x32_bf16(uf[mt][kk], pv1, acc[1][mt], 0, 0, 0);
                acc[2][mt] = __builtin_amdgcn_mfma_f32_16x16x32_bf16(uf[mt][kk], pv2, acc[2][mt], 0, 0, 0);
                acc[3][mt] = __builtin_amdgcn_mfma_f32_16x16x32_bf16(uf[mt][kk], pv3, acc[3][mt], 0, 0, 0);
            }
        }
        // epilogue: e = ebase + mt*16 + l4*4 + r, s = s0 + sg*16 + l15
        #pragma unroll
        for (int sg = 0; sg < 4; sg++) {
            int srow = s0 + sg * 16 + l15;
            #pragma unroll
            for (int mt = 0; mt < 2; mt++) {
                int e0 = ebase + mt * 16 + l4 * 4;
                size_t off = ((size_t)b * S_ + srow) * DM_ + e0;
                float4 h4 = *(const float4*)(hid + off);
                f32x4 a = acc[sg][mt];
                float4 o4;
                o4.x = a[0] + bias[mt].x + h4.x;
                o4.y = a[1] + bias[mt].y + h4.y;
                o4.z = a[2] + bias[mt].z + h4.z;
                o4.w = a[3] + bias[mt].w + h4.w;
                *(float4*)(out + off) = o4;
            }
        }
    }
}

extern "C" void kernel_launch(void* const* d_in, const int* in_sizes, int n_in,
                              void* d_out, int out_size, void* d_ws, size_t ws_size,
                              hipStream_t stream) {
    const float* hid  = (const float*)d_in[0];
    const float* enc  = (const float*)d_in[1];
    const float* wq   = (const float*)d_in[2];
    const float* wk   = (const float*)d_in[3];
    const float* wv   = (const float*)d_in[4];
    const float* wkd  = (const float*)d_in[5];
    const float* wvd  = (const float*)d_in[6];
    const float* wout = (const float*)d_in[7];
    const float* bo   = (const float*)d_in[8];
    float* out = (float*)d_out;

    char* ws = (char*)d_ws;
    unsigned short* At     = (unsigned short*)(ws);               // 15,728,640
    unsigned short* Ut     = (unsigned short*)(ws + 15728640);    // 15,728,640
    unsigned short* KV     = (unsigned short*)(ws + 31457280);    //  3,932,160
    unsigned short* wq_bf  = (unsigned short*)(ws + 35389440);    //  3,276,800
    unsigned short* woutT  = (unsigned short*)(ws + 38666240);    //  3,276,800
    unsigned short* wTk    = (unsigned short*)(ws + 41943040);    //  1,966,080
    unsigned short* wTv    = (unsigned short*)(ws + 43909120);    //  1,966,080
    unsigned short* wTkd   = (unsigned short*)(ws + 45875200);    //  1,966,080
    unsigned short* wTvd   = (unsigned short*)(ws + 47841280);    //  1,966,080 (end 49,807,360)
    unsigned short* Pbuf   = (unsigned short*)(ws + 35389440);    // 50,331,648 — overlaps dead weights (end 85.7 MB)

    k_prep<<<7040, 256, 0, stream>>>(wq, wk, wv, wkd, wvd, wout,
                                     wq_bf, wTk, wTv, wTkd, wTvd, woutT);
    k_projM<<<480, 256, 0, stream>>>(enc, wTk, wTv, wTkd, wTvd, KV);
    k_au<<<768, 256, 0, stream>>>(KV, wq_bf, woutT, At, Ut);
    k_scores2<<<1024, 256, 0, stream>>>(hid, At, Pbuf);
    k_pv<<<1280, 256, 0, stream>>>(Pbuf, Ut, hid, bo, out);
}

// Round 6
// 575.129 us; speedup vs baseline: 1.6644x; 1.6644x over previous
//
#include <hip/hip_runtime.h>
#include <hip/hip_bf16.h>

#define B_ 16
#define S_ 4096
#define DM_ 1280
#define DC_ 768
#define NC_ 384
#define SCALE_ 0.07905694150420949f

typedef __attribute__((ext_vector_type(8))) short bf16x8;
typedef __attribute__((ext_vector_type(4))) float f32x4;
typedef __attribute__((ext_vector_type(4))) unsigned short u16x4;

__device__ __forceinline__ unsigned short f2bf(float f) {
    unsigned int u = __builtin_bit_cast(unsigned int, f);
    u = (u + 0x7FFFu + ((u >> 16) & 1u)) >> 16;
    return (unsigned short)u;
}

__device__ __forceinline__ bf16x8 pack8(float4 x0, float4 x1) {
    bf16x8 a;
    a[0] = __builtin_bit_cast(short, __float2bfloat16(x0.x));
    a[1] = __builtin_bit_cast(short, __float2bfloat16(x0.y));
    a[2] = __builtin_bit_cast(short, __float2bfloat16(x0.z));
    a[3] = __builtin_bit_cast(short, __float2bfloat16(x0.w));
    a[4] = __builtin_bit_cast(short, __float2bfloat16(x1.x));
    a[5] = __builtin_bit_cast(short, __float2bfloat16(x1.y));
    a[6] = __builtin_bit_cast(short, __float2bfloat16(x1.z));
    a[7] = __builtin_bit_cast(short, __float2bfloat16(x1.w));
    return a;
}

__device__ __forceinline__ void gload16(const void* g, void* l) {
    __builtin_amdgcn_global_load_lds(
        (const __attribute__((address_space(1))) void*)g,
        (__attribute__((address_space(3))) void*)l, 16, 0, 0);
}

// ---------- merged prep: wq cvt + 5 transpose/cvt ----------
__device__ __forceinline__ void tcvt_body(const float* __restrict__ in,
                                          unsigned short* __restrict__ out,
                                          int R, int C, int bx, int by, int tid) {
    __shared__ float tile[32][33];
    int c0 = bx * 32, r0 = by * 32;
    int tx = tid & 31, ty = tid >> 5;
    for (int i = ty; i < 32; i += 8)
        tile[i][tx] = in[(size_t)(r0 + i) * C + c0 + tx];
    __syncthreads();
    for (int i = ty; i < 32; i += 8)
        out[(size_t)(c0 + i) * R + r0 + tx] = f2bf(tile[tx][i]);
}

__global__ __launch_bounds__(256)
void k_prep(const float* __restrict__ wq, const float* __restrict__ wk,
            const float* __restrict__ wv, const float* __restrict__ wkd,
            const float* __restrict__ wvd, const float* __restrict__ wout,
            unsigned short* __restrict__ wq_bf, unsigned short* __restrict__ wTk,
            unsigned short* __restrict__ wTv, unsigned short* __restrict__ wTkd,
            unsigned short* __restrict__ wTvd, unsigned short* __restrict__ woutT) {
    int bid = blockIdx.x, tid = threadIdx.x;
    if (bid < 1600) {
        int i = bid * 256 + tid;
        float4 v = ((const float4*)wq)[i];
        u16x4 o = { f2bf(v.x), f2bf(v.y), f2bf(v.z), f2bf(v.w) };
        ((u16x4*)wq_bf)[i] = o;
    } else if (bid < 2560) {
        int r = bid - 1600; tcvt_body(wk,  wTk,  DC_, DM_, r % 40, r / 40, tid);
    } else if (bid < 3520) {
        int r = bid - 2560; tcvt_body(wv,  wTv,  DC_, DM_, r % 40, r / 40, tid);
    } else if (bid < 4480) {
        int r = bid - 3520; tcvt_body(wkd, wTkd, DC_, DM_, r % 40, r / 40, tid);
    } else if (bid < 5440) {
        int r = bid - 4480; tcvt_body(wvd, wTvd, DC_, DM_, r % 40, r / 40, tid);
    } else {
        int r = bid - 5440; tcvt_body(wout, woutT, DM_, DM_, r % 40, r / 40, tid);
    }
}

// ---------- K/V projections via MFMA ----------
__global__ __launch_bounds__(256)
void k_projM(const float* __restrict__ enc,
             const unsigned short* __restrict__ wTk, const unsigned short* __restrict__ wTv,
             const unsigned short* __restrict__ wTkd, const unsigned short* __restrict__ wTvd,
             unsigned short* __restrict__ KV) {
    int bid = blockIdx.x;
    int j = bid / 80, rem = bid % 80, b = rem / 5, nt = rem % 5;
    int tid = threadIdx.x, w = tid >> 6, l = tid & 63, l15 = l & 15, l4 = l >> 4;
    int tok0 = (j < 2) ? 16 : ((j < 4) ? 0 : 32);
    const unsigned short* wT = (j == 0) ? wTk : (j == 1) ? wTv : (j == 2 || j == 4) ? wTkd : wTvd;
    const float* ap = enc + ((size_t)(b * 48 + tok0 + l15)) * DC_;
    f32x4 zero = {0.f, 0.f, 0.f, 0.f};
    f32x4 acc[4];
    #pragma unroll
    for (int t = 0; t < 4; t++) acc[t] = zero;
    for (int kk = 0; kk < 24; kk++) {
        const float4* hp = (const float4*)(ap + kk * 32 + l4 * 8);
        bf16x8 af = pack8(hp[0], hp[1]);
        #pragma unroll
        for (int t = 0; t < 4; t++) {
            int n0 = nt * 256 + w * 64 + t * 16;
            bf16x8 bf = *(const bf16x8*)(wT + (size_t)(n0 + l15) * DC_ + kk * 32 + l4 * 8);
            acc[t] = __builtin_amdgcn_mfma_f32_16x16x32_bf16(af, bf, acc[t], 0, 0, 0);
        }
    }
    #pragma unroll
    for (int t = 0; t < 4; t++) {
        int e = nt * 256 + w * 64 + t * 16 + l15;
        #pragma unroll
        for (int r = 0; r < 4; r++)
            KV[((size_t)(j * 16 + b) * 16 + l4 * 4 + r) * DM_ + e] = f2bf(acc[t][r]);
    }
}

// ---------- merged A/U build via MFMA ----------
__global__ __launch_bounds__(256)
void k_au(const unsigned short* __restrict__ KV, const unsigned short* __restrict__ wqbf,
          const unsigned short* __restrict__ woutT,
          unsigned short* __restrict__ At, unsigned short* __restrict__ Ut) {
    int bid0 = blockIdx.x;
    bool isA = bid0 < 384;
    int bid = isA ? bid0 : bid0 - 384;
    int b = bid & 15, r_ = bid >> 4, x = r_ >> 3, h = r_ & 7;
    int tid = threadIdx.x, w = tid >> 6, l = tid & 63, l15 = l & 15, l4 = l >> 4;
    int jrow = isA ? (2 * x) : (2 * x + 1);
    const unsigned short* wmat = isA ? wqbf : woutT;
    float postscale = isA ? SCALE_ : ((x == 2) ? 1.0f : 0.5f);
    bf16x8 bfr[5];
    #pragma unroll
    for (int kk = 0; kk < 5; kk++)
        bfr[kk] = *(const bf16x8*)(KV + ((size_t)(jrow * 16 + b) * 16 + l15) * DM_ + h * 160 + kk * 32 + l4 * 8);
    f32x4 zero = {0.f, 0.f, 0.f, 0.f};
    for (int tt = 0; tt < 20; tt++) {
        int d0 = w * 320 + tt * 16;
        f32x4 acc = zero;
        #pragma unroll
        for (int kk = 0; kk < 5; kk++) {
            bf16x8 af = *(const bf16x8*)(wmat + (size_t)(d0 + l15) * DM_ + h * 160 + kk * 32 + l4 * 8);
            acc = __builtin_amdgcn_mfma_f32_16x16x32_bf16(af, bfr[kk], acc, 0, 0, 0);
        }
        if (isA) {
            u16x4 pk;
            #pragma unroll
            for (int r = 0; r < 4; r++) pk[r] = f2bf(acc[r] * postscale);
            *(u16x4*)(At + ((size_t)b * NC_ + (x * 8 + h) * 16 + l15) * DM_ + d0 + l4 * 4) = pk;
        } else {
            int c = (x * 8 + h) * 16 + l15;
            #pragma unroll
            for (int r = 0; r < 4; r++)
                Ut[((size_t)b * DM_ + d0 + l4 * 4 + r) * NC_ + c] = f2bf(acc[r] * postscale);
        }
    }
}

// ---------- scores: 64s x 384c block, A staged via global_load_lds ----------
__global__ __launch_bounds__(256, 2)
void k_scores3(const float* __restrict__ hid, const unsigned short* __restrict__ At,
               unsigned short* __restrict__ P) {
    __shared__ unsigned short Apnl[2][NC_ * 32];   // 2 x 24 KB
    int bid = blockIdx.x;
    int orig = (bid & 7) * 128 + (bid >> 3);       // XCD-chunked
    int b = orig >> 6, st = orig & 63;
    int s0 = st * 64;
    int tid = threadIdx.x, w = tid >> 6, l = tid & 63, l15 = l & 15, l4 = l >> 4;
    int rdsw = (l4 ^ ((l15 >> 1) & 3)) * 8;
    const unsigned short* Ab = At + (size_t)b * NC_ * DM_;
    const float* hbase = hid + ((size_t)b * S_ + s0 + l15) * DM_;
    f32x4 zero = {0.f, 0.f, 0.f, 0.f};
    f32x4 acc[4][6];
    #pragma unroll
    for (int si = 0; si < 4; si++)
        #pragma unroll
        for (int cj = 0; cj < 6; cj++) acc[si][cj] = zero;

    // prefetch hid kk=0
    float4 hraw[4][2];
    #pragma unroll
    for (int si = 0; si < 4; si++) {
        hraw[si][0] = *(const float4*)(hbase + (size_t)si * 16 * DM_ + l4 * 8);
        hraw[si][1] = *(const float4*)(hbase + (size_t)si * 16 * DM_ + l4 * 8 + 4);
    }
    // stage A kk=0
    #pragma unroll
    for (int i = 0; i < 6; i++) {
        int idx = i * 256 + tid;
        int c = idx >> 2, m = (idx & 3) ^ ((c >> 1) & 3);
        gload16(Ab + (size_t)c * DM_ + m * 8, (char*)&Apnl[0][0] + idx * 16);
    }
    __syncthreads();

    for (int kk = 0; kk < 40; kk++) {
        int cur = kk & 1;
        bf16x8 hpk[4];
        #pragma unroll
        for (int si = 0; si < 4; si++) hpk[si] = pack8(hraw[si][0], hraw[si][1]);
        if (kk < 39) {
            #pragma unroll
            for (int i = 0; i < 6; i++) {
                int idx = i * 256 + tid;
                int c = idx >> 2, m = (idx & 3) ^ ((c >> 1) & 3);
                gload16(Ab + (size_t)c * DM_ + (kk + 1) * 32 + m * 8,
                        (char*)&Apnl[cur ^ 1][0] + idx * 16);
            }
            #pragma unroll
            for (int si = 0; si < 4; si++) {
                hraw[si][0] = *(const float4*)(hbase + (size_t)si * 16 * DM_ + (kk + 1) * 32 + l4 * 8);
                hraw[si][1] = *(const float4*)(hbase + (size_t)si * 16 * DM_ + (kk + 1) * 32 + l4 * 8 + 4);
            }
        }
        #pragma unroll
        for (int cj = 0; cj < 6; cj++) {
            bf16x8 af = *(const bf16x8*)&Apnl[cur][(w * 96 + cj * 16 + l15) * 32 + rdsw];
            #pragma unroll
            for (int si = 0; si < 4; si++)
                acc[si][cj] = __builtin_amdgcn_mfma_f32_16x16x32_bf16(af, hpk[si], acc[si][cj], 0, 0, 0);
        }
        __syncthreads();
    }

    // softmax per 16-c group (= one cj), write P
    #pragma unroll
    for (int si = 0; si < 4; si++) {
        unsigned short* Pb = P + ((size_t)b * S_ + s0 + si * 16 + l15) * NC_ + w * 96;
        #pragma unroll
        for (int cj = 0; cj < 6; cj++) {
            float v0 = acc[si][cj][0], v1 = acc[si][cj][1], v2 = acc[si][cj][2], v3 = acc[si][cj][3];
            float mx = fmaxf(fmaxf(v0, v1), fmaxf(v2, v3));
            mx = fmaxf(mx, __shfl_xor(mx, 16));
            mx = fmaxf(mx, __shfl_xor(mx, 32));
            float e0 = __expf(v0 - mx), e1 = __expf(v1 - mx), e2 = __expf(v2 - mx), e3 = __expf(v3 - mx);
            float sm = e0 + e1 + e2 + e3;
            sm += __shfl_xor(sm, 16);
            sm += __shfl_xor(sm, 32);
            float rs = 1.0f / sm;
            u16x4 pk = { f2bf(e0 * rs), f2bf(e1 * rs), f2bf(e2 * rs), f2bf(e3 * rs) };
            *(u16x4*)(Pb + cj * 16 + l4 * 4) = pk;
        }
    }
}

// ---------- PV: 128s x 128e block, P+U staged via global_load_lds ----------
__global__ __launch_bounds__(256, 3)
void k_pv2(const unsigned short* __restrict__ P, const unsigned short* __restrict__ Ut,
           const float* __restrict__ hid, const float* __restrict__ bo,
           float* __restrict__ out) {
    __shared__ unsigned short Plds[2][128 * 32];   // 2 x 8 KB
    __shared__ unsigned short Ulds[2][128 * 32];   // 2 x 8 KB
    int bid = blockIdx.x;
    int orig = (bid & 7) * 640 + (bid >> 3);       // XCD-chunked
    int b = orig / 320, rem = orig % 320;
    int st = rem / 10, ec = rem % 10;
    int s0 = st * 128, e0 = ec * 128;
    int tid = threadIdx.x, w = tid >> 6, l = tid & 63, l15 = l & 15, l4 = l >> 4;
    int wr = w >> 1, wc = w & 1;
    int rdsw = (l4 ^ ((l15 >> 1) & 3)) * 8;
    const unsigned short* Pb = P + (size_t)b * S_ * NC_;
    const unsigned short* Ub = Ut + (size_t)b * DM_ * NC_;
    f32x4 zero = {0.f, 0.f, 0.f, 0.f};
    f32x4 acc[4][4];
    #pragma unroll
    for (int si = 0; si < 4; si++)
        #pragma unroll
        for (int ej = 0; ej < 4; ej++) acc[si][ej] = zero;

    // stage kk=0
    #pragma unroll
    for (int i = 0; i < 2; i++) {
        int idx = i * 256 + tid;
        int r = idx >> 2, m = (idx & 3) ^ ((r >> 1) & 3);
        gload16(Pb + (size_t)(s0 + r) * NC_ + m * 8, (char*)&Plds[0][0] + idx * 16);
        gload16(Ub + (size_t)(e0 + r) * NC_ + m * 8, (char*)&Ulds[0][0] + idx * 16);
    }
    __syncthreads();

    for (int kk = 0; kk < 12; kk++) {
        int cur = kk & 1;
        if (kk < 11) {
            #pragma unroll
            for (int i = 0; i < 2; i++) {
                int idx = i * 256 + tid;
                int r = idx >> 2, m = (idx & 3) ^ ((r >> 1) & 3);
                gload16(Pb + (size_t)(s0 + r) * NC_ + (kk + 1) * 32 + m * 8,
                        (char*)&Plds[cur ^ 1][0] + idx * 16);
                gload16(Ub + (size_t)(e0 + r) * NC_ + (kk + 1) * 32 + m * 8,
                        (char*)&Ulds[cur ^ 1][0] + idx * 16);
            }
        }
        bf16x8 uf[4], pf[4];
        #pragma unroll
        for (int ej = 0; ej < 4; ej++)
            uf[ej] = *(const bf16x8*)&Ulds[cur][(wr * 64 + ej * 16 + l15) * 32 + rdsw];
        #pragma unroll
        for (int si = 0; si < 4; si++)
            pf[si] = *(const bf16x8*)&Plds[cur][(wc * 64 + si * 16 + l15) * 32 + rdsw];
        #pragma unroll
        for (int si = 0; si < 4; si++)
            #pragma unroll
            for (int ej = 0; ej < 4; ej++)
                acc[si][ej] = __builtin_amdgcn_mfma_f32_16x16x32_bf16(uf[ej], pf[si], acc[si][ej], 0, 0, 0);
        __syncthreads();
    }

    // epilogue: e = e0 + wr*64 + ej*16 + l4*4 + r (contiguous), s = s0 + wc*64 + si*16 + l15
    float4 b4[4];
    #pragma unroll
    for (int ej = 0; ej < 4; ej++)
        b4[ej] = *(const float4*)(bo + e0 + wr * 64 + ej * 16 + l4 * 4);
    #pragma unroll
    for (int si = 0; si < 4; si++) {
        int srow = s0 + wc * 64 + si * 16 + l15;
        #pragma unroll
        for (int ej = 0; ej < 4; ej++) {
            int ecol = e0 + wr * 64 + ej * 16 + l4 * 4;
            size_t off = ((size_t)b * S_ + srow) * DM_ + ecol;
            float4 h4 = *(const float4*)(hid + off);
            f32x4 a = acc[si][ej];
            float4 o4;
            o4.x = a[0] + b4[ej].x + h4.x;
            o4.y = a[1] + b4[ej].y + h4.y;
            o4.z = a[2] + b4[ej].z + h4.z;
            o4.w = a[3] + b4[ej].w + h4.w;
            *(float4*)(out + off) = o4;
        }
    }
}

extern "C" void kernel_launch(void* const* d_in, const int* in_sizes, int n_in,
                              void* d_out, int out_size, void* d_ws, size_t ws_size,
                              hipStream_t stream) {
    const float* hid  = (const float*)d_in[0];
    const float* enc  = (const float*)d_in[1];
    const float* wq   = (const float*)d_in[2];
    const float* wk   = (const float*)d_in[3];
    const float* wv   = (const float*)d_in[4];
    const float* wkd  = (const float*)d_in[5];
    const float* wvd  = (const float*)d_in[6];
    const float* wout = (const float*)d_in[7];
    const float* bo   = (const float*)d_in[8];
    float* out = (float*)d_out;

    char* ws = (char*)d_ws;
    unsigned short* At     = (unsigned short*)(ws);               // 15,728,640
    unsigned short* Ut     = (unsigned short*)(ws + 15728640);    // 15,728,640
    unsigned short* KV     = (unsigned short*)(ws + 31457280);    //  3,932,160
    unsigned short* wq_bf  = (unsigned short*)(ws + 35389440);    //  3,276,800
    unsigned short* woutT  = (unsigned short*)(ws + 38666240);    //  3,276,800
    unsigned short* wTk    = (unsigned short*)(ws + 41943040);    //  1,966,080
    unsigned short* wTv    = (unsigned short*)(ws + 43909120);    //  1,966,080
    unsigned short* wTkd   = (unsigned short*)(ws + 45875200);    //  1,966,080
    unsigned short* wTvd   = (unsigned short*)(ws + 47841280);    //  1,966,080 (end 49,807,360)
    unsigned short* Pbuf   = (unsigned short*)(ws + 35389440);    // 50,331,648 — overlaps dead weights

    k_prep<<<7040, 256, 0, stream>>>(wq, wk, wv, wkd, wvd, wout,
                                     wq_bf, wTk, wTv, wTkd, wTvd, woutT);
    k_projM<<<480, 256, 0, stream>>>(enc, wTk, wTv, wTkd, wTvd, KV);
    k_au<<<768, 256, 0, stream>>>(KV, wq_bf, woutT, At, Ut);
    k_scores3<<<1024, 256, 0, stream>>>(hid, At, Pbuf);
    k_pv2<<<5120, 256, 0, stream>>>(Pbuf, Ut, hid, bo, out);
}

// Round 7
// 513.006 us; speedup vs baseline: 1.8659x; 1.1211x over previous
//
#include <hip/hip_runtime.h>
#include <hip/hip_bf16.h>

#define B_ 16
#define S_ 4096
#define DM_ 1280
#define DC_ 768
#define NC_ 384
#define SCALE_ 0.07905694150420949f

typedef __attribute__((ext_vector_type(8))) short bf16x8;
typedef __attribute__((ext_vector_type(4))) float f32x4;
typedef __attribute__((ext_vector_type(4))) unsigned short u16x4;

__device__ __forceinline__ unsigned short f2bf(float f) {
    unsigned int u = __builtin_bit_cast(unsigned int, f);
    u = (u + 0x7FFFu + ((u >> 16) & 1u)) >> 16;
    return (unsigned short)u;
}

__device__ __forceinline__ bf16x8 pack8(float4 x0, float4 x1) {
    bf16x8 a;
    a[0] = __builtin_bit_cast(short, __float2bfloat16(x0.x));
    a[1] = __builtin_bit_cast(short, __float2bfloat16(x0.y));
    a[2] = __builtin_bit_cast(short, __float2bfloat16(x0.z));
    a[3] = __builtin_bit_cast(short, __float2bfloat16(x0.w));
    a[4] = __builtin_bit_cast(short, __float2bfloat16(x1.x));
    a[5] = __builtin_bit_cast(short, __float2bfloat16(x1.y));
    a[6] = __builtin_bit_cast(short, __float2bfloat16(x1.z));
    a[7] = __builtin_bit_cast(short, __float2bfloat16(x1.w));
    return a;
}

__device__ __forceinline__ void gload16(const void* g, void* l) {
    __builtin_amdgcn_global_load_lds(
        (const __attribute__((address_space(1))) void*)g,
        (__attribute__((address_space(3))) void*)l, 16, 0, 0);
}

// ---------- merged prep: wq cvt + 5 transpose/cvt ----------
__device__ __forceinline__ void tcvt_body(const float* __restrict__ in,
                                          unsigned short* __restrict__ out,
                                          int R, int C, int bx, int by, int tid) {
    __shared__ float tile[32][33];
    int c0 = bx * 32, r0 = by * 32;
    int tx = tid & 31, ty = tid >> 5;
    for (int i = ty; i < 32; i += 8)
        tile[i][tx] = in[(size_t)(r0 + i) * C + c0 + tx];
    __syncthreads();
    for (int i = ty; i < 32; i += 8)
        out[(size_t)(c0 + i) * R + r0 + tx] = f2bf(tile[tx][i]);
}

__global__ __launch_bounds__(256)
void k_prep(const float* __restrict__ wq, const float* __restrict__ wk,
            const float* __restrict__ wv, const float* __restrict__ wkd,
            const float* __restrict__ wvd, const float* __restrict__ wout,
            unsigned short* __restrict__ wq_bf, unsigned short* __restrict__ wTk,
            unsigned short* __restrict__ wTv, unsigned short* __restrict__ wTkd,
            unsigned short* __restrict__ wTvd, unsigned short* __restrict__ woutT) {
    int bid = blockIdx.x, tid = threadIdx.x;
    if (bid < 1600) {
        int i = bid * 256 + tid;
        float4 v = ((const float4*)wq)[i];
        u16x4 o = { f2bf(v.x), f2bf(v.y), f2bf(v.z), f2bf(v.w) };
        ((u16x4*)wq_bf)[i] = o;
    } else if (bid < 2560) {
        int r = bid - 1600; tcvt_body(wk,  wTk,  DC_, DM_, r % 40, r / 40, tid);
    } else if (bid < 3520) {
        int r = bid - 2560; tcvt_body(wv,  wTv,  DC_, DM_, r % 40, r / 40, tid);
    } else if (bid < 4480) {
        int r = bid - 3520; tcvt_body(wkd, wTkd, DC_, DM_, r % 40, r / 40, tid);
    } else if (bid < 5440) {
        int r = bid - 4480; tcvt_body(wvd, wTvd, DC_, DM_, r % 40, r / 40, tid);
    } else {
        int r = bid - 5440; tcvt_body(wout, woutT, DM_, DM_, r % 40, r / 40, tid);
    }
}

// ---------- K/V projections via MFMA ----------
__global__ __launch_bounds__(256)
void k_projM(const float* __restrict__ enc,
             const unsigned short* __restrict__ wTk, const unsigned short* __restrict__ wTv,
             const unsigned short* __restrict__ wTkd, const unsigned short* __restrict__ wTvd,
             unsigned short* __restrict__ KV) {
    int bid = blockIdx.x;
    int j = bid / 80, rem = bid % 80, b = rem / 5, nt = rem % 5;
    int tid = threadIdx.x, w = tid >> 6, l = tid & 63, l15 = l & 15, l4 = l >> 4;
    int tok0 = (j < 2) ? 16 : ((j < 4) ? 0 : 32);
    const unsigned short* wT = (j == 0) ? wTk : (j == 1) ? wTv : (j == 2 || j == 4) ? wTkd : wTvd;
    const float* ap = enc + ((size_t)(b * 48 + tok0 + l15)) * DC_;
    f32x4 zero = {0.f, 0.f, 0.f, 0.f};
    f32x4 acc[4];
    #pragma unroll
    for (int t = 0; t < 4; t++) acc[t] = zero;
    for (int kk = 0; kk < 24; kk++) {
        const float4* hp = (const float4*)(ap + kk * 32 + l4 * 8);
        bf16x8 af = pack8(hp[0], hp[1]);
        #pragma unroll
        for (int t = 0; t < 4; t++) {
            int n0 = nt * 256 + w * 64 + t * 16;
            bf16x8 bf = *(const bf16x8*)(wT + (size_t)(n0 + l15) * DC_ + kk * 32 + l4 * 8);
            acc[t] = __builtin_amdgcn_mfma_f32_16x16x32_bf16(af, bf, acc[t], 0, 0, 0);
        }
    }
    #pragma unroll
    for (int t = 0; t < 4; t++) {
        int e = nt * 256 + w * 64 + t * 16 + l15;
        #pragma unroll
        for (int r = 0; r < 4; r++)
            KV[((size_t)(j * 16 + b) * 16 + l4 * 4 + r) * DM_ + e] = f2bf(acc[t][r]);
    }
}

// ---------- merged A/U build; outputs kk-major layouts ----------
// At2[b][40][384c][32d], Ut2[b][12][1280e][32c]
__global__ __launch_bounds__(256)
void k_au(const unsigned short* __restrict__ KV, const unsigned short* __restrict__ wqbf,
          const unsigned short* __restrict__ woutT,
          unsigned short* __restrict__ At2, unsigned short* __restrict__ Ut2) {
    int bid0 = blockIdx.x;
    bool isA = bid0 < 384;
    int bid = isA ? bid0 : bid0 - 384;
    int b = bid & 15, r_ = bid >> 4, x = r_ >> 3, h = r_ & 7;
    int tid = threadIdx.x, w = tid >> 6, l = tid & 63, l15 = l & 15, l4 = l >> 4;
    int xh = x * 8 + h;
    int jrow = isA ? (2 * x) : (2 * x + 1);
    const unsigned short* wmat = isA ? wqbf : woutT;
    float postscale = isA ? SCALE_ : ((x == 2) ? 1.0f : 0.5f);
    bf16x8 bfr[5];
    #pragma unroll
    for (int kk = 0; kk < 5; kk++)
        bfr[kk] = *(const bf16x8*)(KV + ((size_t)(jrow * 16 + b) * 16 + l15) * DM_ + h * 160 + kk * 32 + l4 * 8);
    f32x4 zero = {0.f, 0.f, 0.f, 0.f};
    for (int tt = 0; tt < 20; tt++) {
        int d0 = w * 320 + tt * 16;
        f32x4 acc = zero;
        if (isA) {
            #pragma unroll
            for (int kk = 0; kk < 5; kk++) {
                bf16x8 af = *(const bf16x8*)(wmat + (size_t)(d0 + l15) * DM_ + h * 160 + kk * 32 + l4 * 8);
                acc = __builtin_amdgcn_mfma_f32_16x16x32_bf16(af, bfr[kk], acc, 0, 0, 0);
            }
            // D rows = d (l4*4+r), cols = token (l15); c = xh*16 + l15
            int c = xh * 16 + l15;
            u16x4 pk;
            #pragma unroll
            for (int r = 0; r < 4; r++) pk[r] = f2bf(acc[r] * postscale);
            *(u16x4*)(At2 + ((size_t)(b * 40 + (d0 >> 5)) * NC_ + c) * 32 + (d0 & 31) + l4 * 4) = pk;
        } else {
            #pragma unroll
            for (int kk = 0; kk < 5; kk++) {
                bf16x8 af = *(const bf16x8*)(wmat + (size_t)(d0 + l15) * DM_ + h * 160 + kk * 32 + l4 * 8);
                acc = __builtin_amdgcn_mfma_f32_16x16x32_bf16(bfr[kk], af, acc, 0, 0, 0);
            }
            // swapped: D rows = token (l4*4+r), cols = e (l15); c = xh*16 + l4*4 + r
            int e = d0 + l15;
            u16x4 pk;
            #pragma unroll
            for (int r = 0; r < 4; r++) pk[r] = f2bf(acc[r] * postscale);
            *(u16x4*)(Ut2 + ((size_t)(b * 12 + (xh >> 1)) * DM_ + e) * 32 + (xh & 1) * 16 + l4 * 4) = pk;
        }
    }
}

// ---------- scores: A staged from kk-major At2 (contiguous bursts), P -> LDS -> P2 ----------
__global__ __launch_bounds__(256, 2)
void k_scores4(const float* __restrict__ hid, const unsigned short* __restrict__ At2,
               unsigned short* __restrict__ P2) {
    __shared__ char smem[49152];                 // A dbuf 2x24KB; then P 48KB
    unsigned short* Apnl = (unsigned short*)smem;
    int bid = blockIdx.x;
    int orig = (bid & 7) * 128 + (bid >> 3);     // XCD-chunked
    int b = orig >> 6, st = orig & 63;
    int s0 = st * 64;
    int tid = threadIdx.x, w = tid >> 6, l = tid & 63, l15 = l & 15, l4 = l >> 4;
    int rdsw = (l4 ^ ((l15 >> 1) & 3)) * 8;
    const unsigned short* Ab = At2 + (size_t)b * 40 * NC_ * 32;
    const float* hbase = hid + ((size_t)b * S_ + s0 + l15) * DM_;
    f32x4 zero = {0.f, 0.f, 0.f, 0.f};
    f32x4 acc[4][6];
    #pragma unroll
    for (int si = 0; si < 4; si++)
        #pragma unroll
        for (int cj = 0; cj < 6; cj++) acc[si][cj] = zero;

    float4 hraw[4][2];
    #pragma unroll
    for (int si = 0; si < 4; si++) {
        hraw[si][0] = *(const float4*)(hbase + (size_t)si * 16 * DM_ + l4 * 8);
        hraw[si][1] = *(const float4*)(hbase + (size_t)si * 16 * DM_ + l4 * 8 + 4);
    }
    #pragma unroll
    for (int i = 0; i < 6; i++) {                // kk=0 slab: contiguous 24KB
        int idx = i * 256 + tid;
        int c = idx >> 2, m = (idx & 3) ^ ((c >> 1) & 3);
        gload16(Ab + (size_t)c * 32 + m * 8, smem + idx * 16);
    }
    __syncthreads();

    for (int kk = 0; kk < 40; kk++) {
        int cur = kk & 1;
        bf16x8 hpk[4];
        #pragma unroll
        for (int si = 0; si < 4; si++) hpk[si] = pack8(hraw[si][0], hraw[si][1]);
        if (kk < 39) {
            const unsigned short* slab = Ab + (size_t)(kk + 1) * NC_ * 32;
            #pragma unroll
            for (int i = 0; i < 6; i++) {
                int idx = i * 256 + tid;
                int c = idx >> 2, m = (idx & 3) ^ ((c >> 1) & 3);
                gload16(slab + (size_t)c * 32 + m * 8, smem + (cur ^ 1) * 24576 + idx * 16);
            }
            #pragma unroll
            for (int si = 0; si < 4; si++) {
                hraw[si][0] = *(const float4*)(hbase + (size_t)si * 16 * DM_ + (kk + 1) * 32 + l4 * 8);
                hraw[si][1] = *(const float4*)(hbase + (size_t)si * 16 * DM_ + (kk + 1) * 32 + l4 * 8 + 4);
            }
        }
        #pragma unroll
        for (int cj = 0; cj < 6; cj++) {
            bf16x8 af = *(const bf16x8*)&Apnl[cur * 12288 + (w * 96 + cj * 16 + l15) * 32 + rdsw];
            #pragma unroll
            for (int si = 0; si < 4; si++)
                acc[si][cj] = __builtin_amdgcn_mfma_f32_16x16x32_bf16(af, hpk[si], acc[si][cj], 0, 0, 0);
        }
        __syncthreads();
    }

    // softmax per 16-c group; write P into LDS layout [kk2][64 s][32 c] (4KB slabs)
    #pragma unroll
    for (int si = 0; si < 4; si++) {
        int s_l = si * 16 + l15;
        #pragma unroll
        for (int cj = 0; cj < 6; cj++) {
            float v0 = acc[si][cj][0], v1 = acc[si][cj][1], v2 = acc[si][cj][2], v3 = acc[si][cj][3];
            float mx = fmaxf(fmaxf(v0, v1), fmaxf(v2, v3));
            mx = fmaxf(mx, __shfl_xor(mx, 16));
            mx = fmaxf(mx, __shfl_xor(mx, 32));
            float e0 = __expf(v0 - mx), e1 = __expf(v1 - mx), e2 = __expf(v2 - mx), e3 = __expf(v3 - mx);
            float sm = e0 + e1 + e2 + e3;
            sm += __shfl_xor(sm, 16);
            sm += __shfl_xor(sm, 32);
            float rs = 1.0f / sm;
            u16x4 pk = { f2bf(e0 * rs), f2bf(e1 * rs), f2bf(e2 * rs), f2bf(e3 * rs) };
            int c = w * 96 + cj * 16 + l4 * 4;
            *(u16x4*)(smem + (c >> 5) * 4096 + s_l * 64 + (c & 31) * 2) = pk;
        }
    }
    __syncthreads();

    // coalesced copy-out: P2[b][kk2][s][32]
    unsigned short* P2b = P2 + (size_t)b * 12 * S_ * 32;
    #pragma unroll
    for (int i = 0; i < 12; i++) {
        int sl = tid >> 2, m = tid & 3;
        uint4 v = *(const uint4*)(smem + i * 4096 + sl * 64 + m * 16);
        *(uint4*)(P2b + ((size_t)i * S_ + s0 + sl) * 32 + m * 8) = v;
    }
}

// ---------- PV: 128s x 128e, P2/Ut2 staged as contiguous 8KB bursts ----------
__global__ __launch_bounds__(256, 2)
void k_pv3(const unsigned short* __restrict__ P2, const unsigned short* __restrict__ Ut2,
           const float* __restrict__ hid, const float* __restrict__ bo,
           float* __restrict__ out) {
    __shared__ unsigned short Plds[2][4096];     // 2 x 8 KB
    __shared__ unsigned short Ulds[2][4096];     // 2 x 8 KB
    int bid = blockIdx.x;
    int orig = (bid & 7) * 640 + (bid >> 3);     // XCD-chunked
    int b = orig / 320, rem = orig % 320;
    int st = rem / 10, ec = rem % 10;
    int s0 = st * 128, e0 = ec * 128;
    int tid = threadIdx.x, w = tid >> 6, l = tid & 63, l15 = l & 15, l4 = l >> 4;
    int wr = w >> 1, wc = w & 1;
    int rdsw = (l4 ^ ((l15 >> 1) & 3)) * 8;
    const unsigned short* Pb = P2 + (size_t)b * 12 * S_ * 32;
    const unsigned short* Ub = Ut2 + (size_t)b * 12 * DM_ * 32;
    f32x4 zero = {0.f, 0.f, 0.f, 0.f};
    f32x4 acc[4][4];
    #pragma unroll
    for (int si = 0; si < 4; si++)
        #pragma unroll
        for (int ej = 0; ej < 4; ej++) acc[si][ej] = zero;

    #pragma unroll
    for (int i = 0; i < 2; i++) {
        int idx = i * 256 + tid;
        int r = idx >> 2, m = (idx & 3) ^ ((r >> 1) & 3);
        gload16(Pb + ((size_t)s0 + r) * 32 + m * 8, (char*)&Plds[0][0] + idx * 16);
        gload16(Ub + ((size_t)e0 + r) * 32 + m * 8, (char*)&Ulds[0][0] + idx * 16);
    }
    __syncthreads();

    for (int kk = 0; kk < 12; kk++) {
        int cur = kk & 1;
        if (kk < 11) {
            const unsigned short* Pslab = Pb + (size_t)(kk + 1) * S_ * 32;
            const unsigned short* Uslab = Ub + (size_t)(kk + 1) * DM_ * 32;
            #pragma unroll
            for (int i = 0; i < 2; i++) {
                int idx = i * 256 + tid;
                int r = idx >> 2, m = (idx & 3) ^ ((r >> 1) & 3);
                gload16(Pslab + ((size_t)s0 + r) * 32 + m * 8,
                        (char*)&Plds[cur ^ 1][0] + idx * 16);
                gload16(Uslab + ((size_t)e0 + r) * 32 + m * 8,
                        (char*)&Ulds[cur ^ 1][0] + idx * 16);
            }
        }
        bf16x8 uf[4], pf[4];
        #pragma unroll
        for (int ej = 0; ej < 4; ej++)
            uf[ej] = *(const bf16x8*)&Ulds[cur][(wr * 64 + ej * 16 + l15) * 32 + rdsw];
        #pragma unroll
        for (int si = 0; si < 4; si++)
            pf[si] = *(const bf16x8*)&Plds[cur][(wc * 64 + si * 16 + l15) * 32 + rdsw];
        #pragma unroll
        for (int si = 0; si < 4; si++)
            #pragma unroll
            for (int ej = 0; ej < 4; ej++)
                acc[si][ej] = __builtin_amdgcn_mfma_f32_16x16x32_bf16(uf[ej], pf[si], acc[si][ej], 0, 0, 0);
        __syncthreads();
    }

    float4 b4[4];
    #pragma unroll
    for (int ej = 0; ej < 4; ej++)
        b4[ej] = *(const float4*)(bo + e0 + wr * 64 + ej * 16 + l4 * 4);
    #pragma unroll
    for (int si = 0; si < 4; si++) {
        int srow = s0 + wc * 64 + si * 16 + l15;
        #pragma unroll
        for (int ej = 0; ej < 4; ej++) {
            int ecol = e0 + wr * 64 + ej * 16 + l4 * 4;
            size_t off = ((size_t)b * S_ + srow) * DM_ + ecol;
            float4 h4 = *(const float4*)(hid + off);
            f32x4 a = acc[si][ej];
            float4 o4;
            o4.x = a[0] + b4[ej].x + h4.x;
            o4.y = a[1] + b4[ej].y + h4.y;
            o4.z = a[2] + b4[ej].z + h4.z;
            o4.w = a[3] + b4[ej].w + h4.w;
            *(float4*)(out + off) = o4;
        }
    }
}

extern "C" void kernel_launch(void* const* d_in, const int* in_sizes, int n_in,
                              void* d_out, int out_size, void* d_ws, size_t ws_size,
                              hipStream_t stream) {
    const float* hid  = (const float*)d_in[0];
    const float* enc  = (const float*)d_in[1];
    const float* wq   = (const float*)d_in[2];
    const float* wk   = (const float*)d_in[3];
    const float* wv   = (const float*)d_in[4];
    const float* wkd  = (const float*)d_in[5];
    const float* wvd  = (const float*)d_in[6];
    const float* wout = (const float*)d_in[7];
    const float* bo   = (const float*)d_in[8];
    float* out = (float*)d_out;

    char* ws = (char*)d_ws;
    unsigned short* At2    = (unsigned short*)(ws);               // 15,728,640
    unsigned short* Ut2    = (unsigned short*)(ws + 15728640);    // 15,728,640
    unsigned short* KV     = (unsigned short*)(ws + 31457280);    //  3,932,160
    unsigned short* wq_bf  = (unsigned short*)(ws + 35389440);    //  3,276,800
    unsigned short* woutT  = (unsigned short*)(ws + 38666240);    //  3,276,800
    unsigned short* wTk    = (unsigned short*)(ws + 41943040);    //  1,966,080
    unsigned short* wTv    = (unsigned short*)(ws + 43909120);    //  1,966,080
    unsigned short* wTkd   = (unsigned short*)(ws + 45875200);    //  1,966,080
    unsigned short* wTvd   = (unsigned short*)(ws + 47841280);    //  1,966,080 (end 49,807,360)
    unsigned short* P2     = (unsigned short*)(ws + 35389440);    // 50,331,648 — overlaps dead weights

    k_prep<<<7040, 256, 0, stream>>>(wq, wk, wv, wkd, wvd, wout,
                                     wq_bf, wTk, wTv, wTkd, wTvd, woutT);
    k_projM<<<480, 256, 0, stream>>>(enc, wTk, wTv, wTkd, wTvd, KV);
    k_au<<<768, 256, 0, stream>>>(KV, wq_bf, woutT, At2, Ut2);
    k_scores4<<<1024, 256, 0, stream>>>(hid, At2, P2);
    k_pv3<<<5120, 256, 0, stream>>>(P2, Ut2, hid, bo, out);
}

// Round 10
// 398.437 us; speedup vs baseline: 2.4025x; 1.2875x over previous
//
#include <hip/hip_runtime.h>
#include <hip/hip_bf16.h>

#define B_ 16
#define S_ 4096
#define DM_ 1280
#define DC_ 768
#define NC_ 384
#define SCALE_ 0.07905694150420949f

typedef __attribute__((ext_vector_type(8))) short bf16x8;
typedef __attribute__((ext_vector_type(4))) float f32x4;
typedef __attribute__((ext_vector_type(4))) unsigned short u16x4;

#define S_BARRIER() asm volatile("s_barrier" ::: "memory")
#define WAIT_VM(n) asm volatile("s_waitcnt vmcnt(" #n ")" ::: "memory")
#define WAIT_LGKM0() asm volatile("s_waitcnt lgkmcnt(0)" ::: "memory")

__device__ __forceinline__ unsigned short f2bf(float f) {
    unsigned int u = __builtin_bit_cast(unsigned int, f);
    u = (u + 0x7FFFu + ((u >> 16) & 1u)) >> 16;
    return (unsigned short)u;
}

__device__ __forceinline__ bf16x8 pack8(float4 x0, float4 x1) {
    bf16x8 a;
    a[0] = __builtin_bit_cast(short, __float2bfloat16(x0.x));
    a[1] = __builtin_bit_cast(short, __float2bfloat16(x0.y));
    a[2] = __builtin_bit_cast(short, __float2bfloat16(x0.z));
    a[3] = __builtin_bit_cast(short, __float2bfloat16(x0.w));
    a[4] = __builtin_bit_cast(short, __float2bfloat16(x1.x));
    a[5] = __builtin_bit_cast(short, __float2bfloat16(x1.y));
    a[6] = __builtin_bit_cast(short, __float2bfloat16(x1.z));
    a[7] = __builtin_bit_cast(short, __float2bfloat16(x1.w));
    return a;
}

__device__ __forceinline__ void gload16(const void* g, void* l) {
    __builtin_amdgcn_global_load_lds(
        (const __attribute__((address_space(1))) void*)g,
        (__attribute__((address_space(3))) void*)l, 16, 0, 0);
}

// ---------- merged prep: wq cvt + 5 transpose/cvt ----------
__device__ __forceinline__ void tcvt_body(const float* __restrict__ in,
                                          unsigned short* __restrict__ out,
                                          int R, int C, int bx, int by, int tid) {
    __shared__ float tile[32][33];
    int c0 = bx * 32, r0 = by * 32;
    int tx = tid & 31, ty = tid >> 5;
    for (int i = ty; i < 32; i += 8)
        tile[i][tx] = in[(size_t)(r0 + i) * C + c0 + tx];
    __syncthreads();
    for (int i = ty; i < 32; i += 8)
        out[(size_t)(c0 + i) * R + r0 + tx] = f2bf(tile[tx][i]);
}

__global__ __launch_bounds__(256)
void k_prep(const float* __restrict__ wq, const float* __restrict__ wk,
            const float* __restrict__ wv, const float* __restrict__ wkd,
            const float* __restrict__ wvd, const float* __restrict__ wout,
            unsigned short* __restrict__ wq_bf, unsigned short* __restrict__ wTk,
            unsigned short* __restrict__ wTv, unsigned short* __restrict__ wTkd,
            unsigned short* __restrict__ wTvd, unsigned short* __restrict__ woutT) {
    int bid = blockIdx.x, tid = threadIdx.x;
    if (bid < 1600) {
        int i = bid * 256 + tid;
        float4 v = ((const float4*)wq)[i];
        u16x4 o = { f2bf(v.x), f2bf(v.y), f2bf(v.z), f2bf(v.w) };
        ((u16x4*)wq_bf)[i] = o;
    } else if (bid < 2560) {
        int r = bid - 1600; tcvt_body(wk,  wTk,  DC_, DM_, r % 40, r / 40, tid);
    } else if (bid < 3520) {
        int r = bid - 2560; tcvt_body(wv,  wTv,  DC_, DM_, r % 40, r / 40, tid);
    } else if (bid < 4480) {
        int r = bid - 3520; tcvt_body(wkd, wTkd, DC_, DM_, r % 40, r / 40, tid);
    } else if (bid < 5440) {
        int r = bid - 4480; tcvt_body(wvd, wTvd, DC_, DM_, r % 40, r / 40, tid);
    } else {
        int r = bid - 5440; tcvt_body(wout, woutT, DM_, DM_, r % 40, r / 40, tid);
    }
}

// ---------- K/V projections via MFMA ----------
__global__ __launch_bounds__(256)
void k_projM(const float* __restrict__ enc,
             const unsigned short* __restrict__ wTk, const unsigned short* __restrict__ wTv,
             const unsigned short* __restrict__ wTkd, const unsigned short* __restrict__ wTvd,
             unsigned short* __restrict__ KV) {
    int bid = blockIdx.x;
    int j = bid / 80, rem = bid % 80, b = rem / 5, nt = rem % 5;
    int tid = threadIdx.x, w = tid >> 6, l = tid & 63, l15 = l & 15, l4 = l >> 4;
    int tok0 = (j < 2) ? 16 : ((j < 4) ? 0 : 32);
    const unsigned short* wT = (j == 0) ? wTk : (j == 1) ? wTv : (j == 2 || j == 4) ? wTkd : wTvd;
    const float* ap = enc + ((size_t)(b * 48 + tok0 + l15)) * DC_;
    f32x4 zero = {0.f, 0.f, 0.f, 0.f};
    f32x4 acc[4];
    #pragma unroll
    for (int t = 0; t < 4; t++) acc[t] = zero;
    for (int kk = 0; kk < 24; kk++) {
        const float4* hp = (const float4*)(ap + kk * 32 + l4 * 8);
        bf16x8 af = pack8(hp[0], hp[1]);
        #pragma unroll
        for (int t = 0; t < 4; t++) {
            int n0 = nt * 256 + w * 64 + t * 16;
            bf16x8 bf = *(const bf16x8*)(wT + (size_t)(n0 + l15) * DC_ + kk * 32 + l4 * 8);
            acc[t] = __builtin_amdgcn_mfma_f32_16x16x32_bf16(af, bf, acc[t], 0, 0, 0);
        }
    }
    #pragma unroll
    for (int t = 0; t < 4; t++) {
        int e = nt * 256 + w * 64 + t * 16 + l15;
        #pragma unroll
        for (int r = 0; r < 4; r++)
            KV[((size_t)(j * 16 + b) * 16 + l4 * 4 + r) * DM_ + e] = f2bf(acc[t][r]);
    }
}

// ---------- merged A/U build; outputs kk-major layouts ----------
// At2[b][40][384c][32d], Ut2[b][12][1280e][32c]
__global__ __launch_bounds__(256)
void k_au(const unsigned short* __restrict__ KV, const unsigned short* __restrict__ wqbf,
          const unsigned short* __restrict__ woutT,
          unsigned short* __restrict__ At2, unsigned short* __restrict__ Ut2) {
    int bid0 = blockIdx.x;
    bool isA = bid0 < 384;
    int bid = isA ? bid0 : bid0 - 384;
    int b = bid & 15, r_ = bid >> 4, x = r_ >> 3, h = r_ & 7;
    int tid = threadIdx.x, w = tid >> 6, l = tid & 63, l15 = l & 15, l4 = l >> 4;
    int xh = x * 8 + h;
    int jrow = isA ? (2 * x) : (2 * x + 1);
    const unsigned short* wmat = isA ? wqbf : woutT;
    float postscale = isA ? SCALE_ : ((x == 2) ? 1.0f : 0.5f);
    bf16x8 bfr[5];
    #pragma unroll
    for (int kk = 0; kk < 5; kk++)
        bfr[kk] = *(const bf16x8*)(KV + ((size_t)(jrow * 16 + b) * 16 + l15) * DM_ + h * 160 + kk * 32 + l4 * 8);
    f32x4 zero = {0.f, 0.f, 0.f, 0.f};
    for (int tt = 0; tt < 20; tt++) {
        int d0 = w * 320 + tt * 16;
        f32x4 acc = zero;
        if (isA) {
            #pragma unroll
            for (int kk = 0; kk < 5; kk++) {
                bf16x8 af = *(const bf16x8*)(wmat + (size_t)(d0 + l15) * DM_ + h * 160 + kk * 32 + l4 * 8);
                acc = __builtin_amdgcn_mfma_f32_16x16x32_bf16(af, bfr[kk], acc, 0, 0, 0);
            }
            int c = xh * 16 + l15;
            u16x4 pk;
            #pragma unroll
            for (int r = 0; r < 4; r++) pk[r] = f2bf(acc[r] * postscale);
            *(u16x4*)(At2 + ((size_t)(b * 40 + (d0 >> 5)) * NC_ + c) * 32 + (d0 & 31) + l4 * 4) = pk;
        } else {
            #pragma unroll
            for (int kk = 0; kk < 5; kk++) {
                bf16x8 af = *(const bf16x8*)(wmat + (size_t)(d0 + l15) * DM_ + h * 160 + kk * 32 + l4 * 8);
                acc = __builtin_amdgcn_mfma_f32_16x16x32_bf16(bfr[kk], af, acc, 0, 0, 0);
            }
            int e = d0 + l15;
            u16x4 pk;
            #pragma unroll
            for (int r = 0; r < 4; r++) pk[r] = f2bf(acc[r] * postscale);
            *(u16x4*)(Ut2 + ((size_t)(b * 12 + (xh >> 1)) * DM_ + e) * 32 + (xh & 1) * 16 + l4 * 4) = pk;
        }
    }
}

// ---------- scores: UNIFORM gload_lds pipeline (A 24KB + H 8KB per kk), counted vmcnt ----------
__global__ __launch_bounds__(256, 2)
void k_scores6(const float* __restrict__ hid, const unsigned short* __restrict__ At2,
               unsigned short* __restrict__ P2) {
    __shared__ char smem[65536];                 // A dbuf 2x24KB @0; H dbuf 2x8KB @48K; P reuses 0..48K
    unsigned short* Apnl = (unsigned short*)smem;
    char* Hlds = smem + 49152;
    int bid = blockIdx.x;
    int orig = (bid & 7) * 128 + (bid >> 3);     // XCD-chunked
    int b = orig >> 6, st = orig & 63;
    int s0 = st * 64;
    int tid = threadIdx.x, w = tid >> 6, l = tid & 63, l15 = l & 15, l4 = l >> 4;
    int rdsw = (l4 ^ ((l15 >> 1) & 3)) * 8;
    const unsigned short* Ab = At2 + (size_t)b * 40 * NC_ * 32;
    const float* hsrc = hid + ((size_t)b * S_ + s0) * DM_;
    f32x4 zero = {0.f, 0.f, 0.f, 0.f};
    f32x4 acc[4][6];
    #pragma unroll
    for (int si = 0; si < 4; si++)
        #pragma unroll
        for (int cj = 0; cj < 6; cj++) acc[si][cj] = zero;

    // one staging region = 8 gload_lds (6 A + 2 H) -- single uniform VMEM stream
    auto stageAH = [&](int kk, int buf) {
        const unsigned short* slab = Ab + (size_t)kk * (NC_ * 32);
        #pragma unroll
        for (int i = 0; i < 6; i++) {
            int idx = i * 256 + tid;
            int c = idx >> 2, m = (idx & 3) ^ ((c >> 1) & 3);
            gload16(slab + (size_t)c * 32 + m * 8, smem + buf * 24576 + idx * 16);
        }
        #pragma unroll
        for (int i = 0; i < 2; i++) {
            int idx = i * 256 + tid;
            int r = idx >> 3, sg = (idx & 7) ^ (r & 7);   // granule pre-swizzle for 128B-stride rows
            gload16(hsrc + (size_t)r * DM_ + kk * 32 + sg * 4, Hlds + buf * 8192 + idx * 16);
        }
    };
    auto compute = [&](int cur) {
        bf16x8 hpk[4];
        #pragma unroll
        for (int si = 0; si < 4; si++) {
            int r = si * 16 + l15;
            float4 lo = *(const float4*)(Hlds + cur * 8192 + r * 128 + (((2 * l4) ^ (l15 & 7)) * 16));
            float4 hi = *(const float4*)(Hlds + cur * 8192 + r * 128 + (((2 * l4 + 1) ^ (l15 & 7)) * 16));
            hpk[si] = pack8(lo, hi);
        }
        __builtin_amdgcn_s_setprio(1);
        #pragma unroll
        for (int cj = 0; cj < 6; cj++) {
            bf16x8 af = *(const bf16x8*)&Apnl[cur * 12288 + (w * 96 + cj * 16 + l15) * 32 + rdsw];
            #pragma unroll
            for (int si = 0; si < 4; si++)
                acc[si][cj] = __builtin_amdgcn_mfma_f32_16x16x32_bf16(af, hpk[si], acc[si][cj], 0, 0, 0);
        }
        __builtin_amdgcn_s_setprio(0);
    };

    stageAH(0, 0);
    for (int kk = 0; kk < 39; kk++) {
        int cur = kk & 1;
        stageAH(kk + 1, cur ^ 1);   // issue next tile: 8 loads
        WAIT_VM(8);                 // drain exactly tile kk's 8 (uniform stream, in-order)
        S_BARRIER();
        compute(cur);
        WAIT_LGKM0();               // close LDS reads before next overwrite
        S_BARRIER();
    }
    WAIT_VM(0);
    S_BARRIER();
    compute(1);                     // kk=39 staged into buffer 1
    WAIT_LGKM0();
    S_BARRIER();

    // softmax per 16-c group; P into LDS [kk2][64 s][32 c] with chunk-XOR on (s&3)
    #pragma unroll
    for (int si = 0; si < 4; si++) {
        int s_l = si * 16 + l15;
        #pragma unroll
        for (int cj = 0; cj < 6; cj++) {
            float v0 = acc[si][cj][0], v1 = acc[si][cj][1], v2 = acc[si][cj][2], v3 = acc[si][cj][3];
            float mx = fmaxf(fmaxf(v0, v1), fmaxf(v2, v3));
            mx = fmaxf(mx, __shfl_xor(mx, 16));
            mx = fmaxf(mx, __shfl_xor(mx, 32));
            float e0 = __expf(v0 - mx), e1 = __expf(v1 - mx), e2 = __expf(v2 - mx), e3 = __expf(v3 - mx);
            float sm = e0 + e1 + e2 + e3;
            sm += __shfl_xor(sm, 16);
            sm += __shfl_xor(sm, 32);
            float rs = 1.0f / sm;
            u16x4 pk = { f2bf(e0 * rs), f2bf(e1 * rs), f2bf(e2 * rs), f2bf(e3 * rs) };
            int c = w * 96 + cj * 16 + l4 * 4;
            int chunk = ((c & 31) >> 3) ^ (s_l & 3);
            *(u16x4*)(smem + (c >> 5) * 4096 + s_l * 64 + chunk * 16 + (l4 & 1) * 8) = pk;
        }
    }
    __syncthreads();

    // coalesced copy-out: P2[b][kk2][s][32]
    unsigned short* P2b = P2 + (size_t)b * 12 * S_ * 32;
    #pragma unroll
    for (int i = 0; i < 12; i++) {
        int sl = tid >> 2, m = tid & 3;
        uint4 v = *(const uint4*)(smem + i * 4096 + sl * 64 + ((m ^ (sl & 3)) * 16));
        *(uint4*)(P2b + ((size_t)i * S_ + s0 + sl) * 32 + m * 8) = v;
    }
}

// ---------- PV: counted-vmcnt 3-buffer pipeline (uniform gload_lds stream) ----------
__global__ __launch_bounds__(256, 3)
void k_pv4(const unsigned short* __restrict__ P2, const unsigned short* __restrict__ Ut2,
           const float* __restrict__ hid, const float* __restrict__ bo,
           float* __restrict__ out) {
    __shared__ unsigned short Plds[3 * 4096];    // 3 x 8 KB
    __shared__ unsigned short Ulds[3 * 4096];
    int bid = blockIdx.x;
    int orig = (bid & 7) * 640 + (bid >> 3);     // XCD-chunked
    int b = orig / 320, rem = orig % 320;
    int st = rem / 10, ec = rem % 10;
    int s0 = st * 128, e0 = ec * 128;
    int tid = threadIdx.x, w = tid >> 6, l = tid & 63, l15 = l & 15, l4 = l >> 4;
    int wr = w >> 1, wc = w & 1;
    int rdsw = (l4 ^ ((l15 >> 1) & 3)) * 8;
    const unsigned short* Pb = P2 + (size_t)b * 12 * S_ * 32;
    const unsigned short* Ub = Ut2 + (size_t)b * 12 * DM_ * 32;
    f32x4 zero = {0.f, 0.f, 0.f, 0.f};
    f32x4 acc[4][4];
    #pragma unroll
    for (int si = 0; si < 4; si++)
        #pragma unroll
        for (int ej = 0; ej < 4; ej++) acc[si][ej] = zero;

    auto stage = [&](int kk, int bufsel) {
        const unsigned short* Pslab = Pb + (size_t)kk * S_ * 32;
        const unsigned short* Uslab = Ub + (size_t)kk * DM_ * 32;
        #pragma unroll
        for (int i = 0; i < 2; i++) {
            int idx = i * 256 + tid;
            int r = idx >> 2, m = (idx & 3) ^ ((r >> 1) & 3);
            gload16(Pslab + ((size_t)s0 + r) * 32 + m * 8, (char*)Plds + bufsel * 8192 + idx * 16);
            gload16(Uslab + ((size_t)e0 + r) * 32 + m * 8, (char*)Ulds + bufsel * 8192 + idx * 16);
        }
    };
    auto compute = [&](int cur) {
        bf16x8 uf[4], pf[4];
        #pragma unroll
        for (int ej = 0; ej < 4; ej++)
            uf[ej] = *(const bf16x8*)&Ulds[cur * 4096 + (wr * 64 + ej * 16 + l15) * 32 + rdsw];
        #pragma unroll
        for (int si = 0; si < 4; si++)
            pf[si] = *(const bf16x8*)&Plds[cur * 4096 + (wc * 64 + si * 16 + l15) * 32 + rdsw];
        __builtin_amdgcn_s_setprio(1);
        #pragma unroll
        for (int si = 0; si < 4; si++)
            #pragma unroll
            for (int ej = 0; ej < 4; ej++)
                acc[si][ej] = __builtin_amdgcn_mfma_f32_16x16x32_bf16(uf[ej], pf[si], acc[si][ej], 0, 0, 0);
        __builtin_amdgcn_s_setprio(0);
    };
    auto PITER = [&](int kk, int cur, int tgt) {
        stage(kk + 2, tgt);
        WAIT_VM(8);
        S_BARRIER();
        compute(cur);
        WAIT_LGKM0();
        S_BARRIER();
    };

    stage(0, 0); stage(1, 1);
    for (int k0 = 0; k0 < 9; k0 += 3) {
        PITER(k0 + 0, 0, 2); PITER(k0 + 1, 1, 0); PITER(k0 + 2, 2, 1);
    }
    PITER(9, 0, 2);
    // peel kk=10: queue [st10·4, st11·4] -> vmcnt(4) drains st10
    WAIT_VM(4); S_BARRIER(); compute(1); WAIT_LGKM0(); S_BARRIER();
    // peel kk=11
    WAIT_VM(0); S_BARRIER(); compute(2);

    // epilogue: e = e0 + wr*64 + ej*16 + l4*4 + r, s = s0 + wc*64 + si*16 + l15
    float4 b4[4];
    #pragma unroll
    for (int ej = 0; ej < 4; ej++)
        b4[ej] = *(const float4*)(bo + e0 + wr * 64 + ej * 16 + l4 * 4);
    #pragma unroll
    for (int si = 0; si < 4; si++) {
        int srow = s0 + wc * 64 + si * 16 + l15;
        #pragma unroll
        for (int ej = 0; ej < 4; ej++) {
            int ecol = e0 + wr * 64 + ej * 16 + l4 * 4;
            size_t off = ((size_t)b * S_ + srow) * DM_ + ecol;
            float4 h4 = *(const float4*)(hid + off);
            f32x4 a = acc[si][ej];
            float4 o4;
            o4.x = a[0] + b4[ej].x + h4.x;
            o4.y = a[1] + b4[ej].y + h4.y;
            o4.z = a[2] + b4[ej].z + h4.z;
            o4.w = a[3] + b4[ej].w + h4.w;
            *(float4*)(out + off) = o4;
        }
    }
}

extern "C" void kernel_launch(void* const* d_in, const int* in_sizes, int n_in,
                              void* d_out, int out_size, void* d_ws, size_t ws_size,
                              hipStream_t stream) {
    const float* hid  = (const float*)d_in[0];
    const float* enc  = (const float*)d_in[1];
    const float* wq   = (const float*)d_in[2];
    const float* wk   = (const float*)d_in[3];
    const float* wv   = (const float*)d_in[4];
    const float* wkd  = (const float*)d_in[5];
    const float* wvd  = (const float*)d_in[6];
    const float* wout = (const float*)d_in[7];
    const float* bo   = (const float*)d_in[8];
    float* out = (float*)d_out;

    char* ws = (char*)d_ws;
    unsigned short* At2    = (unsigned short*)(ws);               // 15,728,640
    unsigned short* Ut2    = (unsigned short*)(ws + 15728640);    // 15,728,640
    unsigned short* KV     = (unsigned short*)(ws + 31457280);    //  3,932,160
    unsigned short* wq_bf  = (unsigned short*)(ws + 35389440);    //  3,276,800
    unsigned short* woutT  = (unsigned short*)(ws + 38666240);    //  3,276,800
    unsigned short* wTk    = (unsigned short*)(ws + 41943040);    //  1,966,080
    unsigned short* wTv    = (unsigned short*)(ws + 43909120);    //  1,966,080
    unsigned short* wTkd   = (unsigned short*)(ws + 45875200);    //  1,966,080
    unsigned short* wTvd   = (unsigned short*)(ws + 47841280);    //  1,966,080 (end 49,807,360)
    unsigned short* P2     = (unsigned short*)(ws + 35389440);    // 50,331,648 — overlaps dead weights

    k_prep<<<7040, 256, 0, stream>>>(wq, wk, wv, wkd, wvd, wout,
                                     wq_bf, wTk, wTv, wTkd, wTvd, woutT);
    k_projM<<<480, 256, 0, stream>>>(enc, wTk, wTv, wTkd, wTvd, KV);
    k_au<<<768, 256, 0, stream>>>(KV, wq_bf, woutT, At2, Ut2);
    k_scores6<<<1024, 256, 0, stream>>>(hid, At2, P2);
    k_pv4<<<5120, 256, 0, stream>>>(P2, Ut2, hid, bo, out);
}